// Round 6
// baseline (117.263 us; speedup 1.0000x reference)
//
#include <hip/hip_runtime.h>

#define NB 4
#define TT 512          // TQ = TP
#define DD 256
#define K2L2E    2.885390081777927f     // 2*log2(e): e^{2x} = 2^{K*x}
#define NEG2L2E (-2.885390081777927f)

#if defined(__has_builtin)
# if __has_builtin(__builtin_amdgcn_global_load_lds)
#  define HAS_GLL 1
# endif
#endif

typedef float v2f __attribute__((ext_vector_type(2)));

__device__ __forceinline__ v2f pk_fma(v2f a, v2f b, v2f c) {
#if defined(__has_builtin)
# if __has_builtin(__builtin_elementwise_fma)
    return __builtin_elementwise_fma(a, b, c);
# else
    v2f r; r.x = __builtin_fmaf(a.x, b.x, c.x); r.y = __builtin_fmaf(a.y, b.y, c.y); return r;
# endif
#else
    v2f r; r.x = __builtin_fmaf(a.x, b.x, c.x); r.y = __builtin_fmaf(a.y, b.y, c.y); return r;
#endif
}
__device__ __forceinline__ v2f splat2(float s) { v2f r; r.x = s; r.y = s; return r; }

__device__ __forceinline__ void stage16(const float* __restrict__ g, float* l) {
#ifdef HAS_GLL
    __builtin_amdgcn_global_load_lds((const __attribute__((address_space(1))) void*)g,
                                     (__attribute__((address_space(3))) void*)l, 16, 0, 0);
#else
    *(float4*)l = *(const float4*)g;
#endif
}

// ============ P1: projections + exp epilogue ============
// expQ[b][d][q] = e^{2*(q@W0)[q,d]}            (TRANSPOSED, q-minor)
// expP[b][p][d] = e^{2*(p@W1)[p,d]} / vc[d]    (NATURAL, d-minor; 1/vc FOLDED
//   so P2's reciprocal-batch needs no numerator weights: v/f = 1/(c + a'B))
__global__ __launch_bounds__(256) void proj_exp_kernel(
    const float* __restrict__ qin, const float* __restrict__ pin,
    const float* __restrict__ W0, const float* __restrict__ W1,
    const float* __restrict__ vc,
    float* __restrict__ expQ, float* __restrict__ expP)
{
    const int blk = blockIdx.x;
    const int wh = blk >> 8, tid = blk & 255;
    const int m0 = (tid >> 2) * 32, n0 = (tid & 3) * 64;
    const float* A = wh ? pin : qin;
    const float* W = wh ? W1 : W0;

    __shared__ __align__(16) float As[32 * 34];   // [k][m]
    __shared__ __align__(16) float Bs[32 * 64];   // [k][n]

    const int t  = threadIdx.x;
    const int ar = t >> 3, ac4 = (t & 7) * 4;
    const int br = t >> 4, bc4 = (t & 15) * 4;
    // microtile index roles swap per output orientation (store-coalescing)
    const int tm = wh ? (t >> 4) : (t & 15);
    const int tn = wh ? (t & 15) : (t >> 4);

    const float* Ap = A + (long)(m0 + ar) * DD + ac4;

    float4 av  = *(const float4*)Ap;
    float4 bv0 = *(const float4*)(W + (long)br * DD + n0 + bc4);
    float4 bv1 = *(const float4*)(W + (long)(br + 16) * DD + n0 + bc4);

    v2f accv[2][2];
    accv[0][0] = splat2(0.f); accv[0][1] = splat2(0.f);
    accv[1][0] = splat2(0.f); accv[1][1] = splat2(0.f);

    for (int c = 0; c < 8; ++c) {
        As[(ac4 + 0) * 34 + ar] = av.x;
        As[(ac4 + 1) * 34 + ar] = av.y;
        As[(ac4 + 2) * 34 + ar] = av.z;
        As[(ac4 + 3) * 34 + ar] = av.w;
        *(float4*)&Bs[br * 64 + bc4]        = bv0;
        *(float4*)&Bs[(br + 16) * 64 + bc4] = bv1;
        __syncthreads();
        if (c < 7) {
            int k1 = (c + 1) * 32;
            av  = *(const float4*)(Ap + k1);
            bv0 = *(const float4*)(W + (long)(k1 + br) * DD + n0 + bc4);
            bv1 = *(const float4*)(W + (long)(k1 + 16 + br) * DD + n0 + bc4);
        }
        #pragma unroll
        for (int kk = 0; kk < 32; ++kk) {
            float2 a = *(const float2*)&As[kk * 34 + 2 * tm];
            float4 b = *(const float4*)&Bs[kk * 64 + 4 * tn];
            v2f b01; b01.x = b.x; b01.y = b.y;
            v2f b23; b23.x = b.z; b23.y = b.w;
            accv[0][0] = pk_fma(splat2(a.x), b01, accv[0][0]);
            accv[0][1] = pk_fma(splat2(a.x), b23, accv[0][1]);
            accv[1][0] = pk_fma(splat2(a.y), b01, accv[1][0]);
            accv[1][1] = pk_fma(splat2(a.y), b23, accv[1][1]);
        }
        __syncthreads();
    }

    float acc[2][4];
    #pragma unroll
    for (int i = 0; i < 2; ++i) {
        acc[i][0] = accv[i][0].x; acc[i][1] = accv[i][0].y;
        acc[i][2] = accv[i][1].x; acc[i][3] = accv[i][1].y;
    }

    const int bi = m0 >> 9;
    const int ml = m0 & 511;
    if (wh) {
        // natural: expP[bi][ml+2tm+i][n0+4tn .. +3], float4 store, tn-minor lanes
        // scaled by rcp(vc[d]) (d = col): P2 consumes a' = e^{2x}/v directly.
        float4 vcv = *(const float4*)(vc + n0 + 4 * tn);
        float4 rv;
        rv.x = __builtin_amdgcn_rcpf(vcv.x);
        rv.y = __builtin_amdgcn_rcpf(vcv.y);
        rv.z = __builtin_amdgcn_rcpf(vcv.z);
        rv.w = __builtin_amdgcn_rcpf(vcv.w);
        #pragma unroll
        for (int i = 0; i < 2; ++i) {
            float4 st;
            st.x = __builtin_amdgcn_exp2f(acc[i][0] * K2L2E) * rv.x;
            st.y = __builtin_amdgcn_exp2f(acc[i][1] * K2L2E) * rv.y;
            st.z = __builtin_amdgcn_exp2f(acc[i][2] * K2L2E) * rv.z;
            st.w = __builtin_amdgcn_exp2f(acc[i][3] * K2L2E) * rv.w;
            *(float4*)(expP + ((long)bi * TT + ml + 2 * tm + i) * DD + n0 + 4 * tn) = st;
        }
    } else {
        // transposed: expQ[bi][n0+4tn+j][ml+2tm .. +1], float2 store, tm-minor lanes
        #pragma unroll
        for (int j = 0; j < 4; ++j) {
            int d = n0 + 4 * tn + j;
            float2 st;
            st.x = __builtin_amdgcn_exp2f(acc[0][j] * K2L2E);
            st.y = __builtin_amdgcn_exp2f(acc[1][j] * K2L2E);
            *(float2*)(expQ + ((long)bi * DD + d) * TT + ml + 2 * tm) = st;
        }
    }
}

// ============ P2: scores (v4: d-split + vc-FOLDED pair-reciprocal math) ============
// 64p x 64q tile, 512 thr, d-split halves (h = t>>8), 4p x 4q per thread.
// With 1/vc folded into expP (P1) and c_d = rcp(vc[d]) staged here:
//   v_d/f_d = 1/(c_d + a'_d B_d) = 1/f'_d
//   pair combine: 1/f'0 + 1/f'1 = (f'0+f'1) * rcp(f'0*f'1)
// Per 8 element-ops: 10 pk + 4 rcp = 56 cy (was 14 pk + 2 rcp = 64 cy).
// Full [64p][256d] PA + [256d][64q] QB staged ONCE (132 KB LDS, 1 block/CU);
// A-side conflict-free via d-quad XOR swizzle (row>>2)&7 on the
// global_load_lds SOURCE (linear LDS dest) + same XOR on the read.
__global__ __launch_bounds__(512) void score_kernel(
    const float* __restrict__ expP, const float* __restrict__ expQ,
    const float* __restrict__ vc, float* __restrict__ ebuf, float* __restrict__ lpart)
{
    const int b = blockIdx.z, pt = blockIdx.y, qt = blockIdx.x;
    const int p0 = pt * 64, q0 = qt * 64;
    const int t  = threadIdx.x;            // 0..511
    const int h  = t >> 8;                 // d-half: 0 -> d 0..127, 1 -> d 128..255
    const int u  = t & 255;
    const int qx = u & 15;                 // q = q0 + 4qx + {0..3}
    const int py = u >> 4;                 // p = p0 + 4py + {0..3}
    const int sw = py & 7;                 // A swizzle key = ((4py+i)>>2)&7 = py&7

    __shared__ __align__(16) float PA[64 * 256];   // [p][d], quad-swizzled; 64 KB
    __shared__ __align__(16) float QB[256 * 64];   // [d][q]; 64 KB
    __shared__ __align__(16) float vcs[DD];        // rcp(vc[d])

    const float* gP = expP + ((long)b * TT + p0) * DD;   // natural [p][d] (pre-scaled)
    const float* gQ = expQ + (long)b * DD * TT + q0;     // [d][q]

    // ---- stage everything (async), linear LDS dest, pre-swizzled PA source
    #pragma unroll
    for (int s = 0; s < 8; ++s) {
        int f = t + 512 * s;               // 0..4095
        int pr = f >> 6, j = f & 63;       // row, d-quad
        stage16(gP + (long)pr * DD + 4 * (j ^ ((pr >> 2) & 7)), &PA[f * 4]);
    }
    #pragma unroll
    for (int s = 0; s < 8; ++s) {
        int f = t + 512 * s;
        int d = f >> 4, o4 = (f & 15) * 4;
        stage16(gQ + (long)d * TT + o4, &QB[f * 4]);
    }
    if (t < DD) vcs[t] = __builtin_amdgcn_rcpf(vc[t]);
    __syncthreads();   // drains vmcnt -> all LDS ready

    v2f acc[4][2];
    #pragma unroll
    for (int i = 0; i < 4; ++i) { acc[i][0] = splat2(0.f); acc[i][1] = splat2(0.f); }
    const float* vcb = &vcs[h * 128];

    #pragma unroll 4
    for (int dq = 0; dq < 32; ++dq) {
        const int dj = h * 32 + dq;        // global d-quad index 0..63
        float4 cq = *(const float4*)&vcb[4 * dq];   // rcp(vc) quad
        const int sq = 4 * (dj ^ sw);
        float4 A0 = *(const float4*)&PA[(4 * py + 0) * 256 + sq];
        float4 A1 = *(const float4*)&PA[(4 * py + 1) * 256 + sq];
        float4 A2 = *(const float4*)&PA[(4 * py + 2) * 256 + sq];
        float4 A3 = *(const float4*)&PA[(4 * py + 3) * 256 + sq];
        const int db = (4 * dj) * 64 + 4 * qx;
        float4 B0 = *(const float4*)&QB[db];
        float4 B1 = *(const float4*)&QB[db + 64];
        float4 B2 = *(const float4*)&QB[db + 128];
        float4 B3 = *(const float4*)&QB[db + 192];
        v2f b0l; b0l.x = B0.x; b0l.y = B0.y;  v2f b0h; b0h.x = B0.z; b0h.y = B0.w;
        v2f b1l; b1l.x = B1.x; b1l.y = B1.y;  v2f b1h; b1h.x = B1.z; b1h.y = B1.w;
        v2f b2l; b2l.x = B2.x; b2l.y = B2.y;  v2f b2h; b2h.x = B2.z; b2h.y = B2.w;
        v2f b3l; b3l.x = B3.x; b3l.y = B3.y;  v2f b3h; b3h.x = B3.z; b3h.y = B3.w;
        const v2f c0 = splat2(cq.x), c1 = splat2(cq.y), c2 = splat2(cq.z), c3 = splat2(cq.w);
        #pragma unroll
        for (int i = 0; i < 4; ++i) {
            float4 a = (i == 0) ? A0 : (i == 1) ? A1 : (i == 2) ? A2 : A3;
            {   // q-pair 0 (q0,q1)
                v2f f0 = pk_fma(splat2(a.x), b0l, c0);
                v2f f1 = pk_fma(splat2(a.y), b1l, c1);
                v2f f2 = pk_fma(splat2(a.z), b2l, c2);
                v2f f3 = pk_fma(splat2(a.w), b3l, c3);
                v2f n01 = f0 + f1, d01 = f0 * f1;
                v2f n23 = f2 + f3, d23 = f2 * f3;
                v2f r01, r23;
                r01.x = __builtin_amdgcn_rcpf(d01.x);
                r01.y = __builtin_amdgcn_rcpf(d01.y);
                r23.x = __builtin_amdgcn_rcpf(d23.x);
                r23.y = __builtin_amdgcn_rcpf(d23.y);
                acc[i][0] = pk_fma(n01, r01, acc[i][0]);
                acc[i][0] = pk_fma(n23, r23, acc[i][0]);
            }
            {   // q-pair 1 (q2,q3)
                v2f f0 = pk_fma(splat2(a.x), b0h, c0);
                v2f f1 = pk_fma(splat2(a.y), b1h, c1);
                v2f f2 = pk_fma(splat2(a.z), b2h, c2);
                v2f f3 = pk_fma(splat2(a.w), b3h, c3);
                v2f n01 = f0 + f1, d01 = f0 * f1;
                v2f n23 = f2 + f3, d23 = f2 * f3;
                v2f r01, r23;
                r01.x = __builtin_amdgcn_rcpf(d01.x);
                r01.y = __builtin_amdgcn_rcpf(d01.y);
                r23.x = __builtin_amdgcn_rcpf(d23.x);
                r23.y = __builtin_amdgcn_rcpf(d23.y);
                acc[i][1] = pk_fma(n01, r01, acc[i][1]);
                acc[i][1] = pk_fma(n23, r23, acc[i][1]);
            }
        }
    }

    __syncthreads();                 // all PA/QB reads done; safe to reuse
    // ---- combine halves: h=1 publishes partial acc, h=0 adds + finishes
    float* scr = &PA[0];             // [64p][64q] exchange (16 KB)
    if (h == 1) {
        #pragma unroll
        for (int i = 0; i < 4; ++i) {
            float4 st;
            st.x = acc[i][0].x; st.y = acc[i][0].y;
            st.z = acc[i][1].x; st.w = acc[i][1].y;
            *(float4*)&scr[(4 * py + i) * 64 + 4 * qx] = st;
        }
    }
    __syncthreads();
    float* scr2 = &QB[0];            // [16][64] column partials
    if (h == 0) {
        float* eb = ebuf + ((long)b * TT + p0) * TT + q0;
        float4 colp; colp.x = 0.f; colp.y = 0.f; colp.z = 0.f; colp.w = 0.f;
        #pragma unroll
        for (int i = 0; i < 4; ++i) {
            float4 o = *(const float4*)&scr[(4 * py + i) * 64 + 4 * qx];
            float4 ev;
            ev.x = __builtin_amdgcn_exp2f((acc[i][0].x + o.x) * NEG2L2E);
            ev.y = __builtin_amdgcn_exp2f((acc[i][0].y + o.y) * NEG2L2E);
            ev.z = __builtin_amdgcn_exp2f((acc[i][1].x + o.z) * NEG2L2E);
            ev.w = __builtin_amdgcn_exp2f((acc[i][1].y + o.w) * NEG2L2E);
            *(float4*)(eb + (long)(4 * py + i) * TT + 4 * qx) = ev;
            colp.x += ev.x; colp.y += ev.y; colp.z += ev.z; colp.w += ev.w;
        }
        *(float4*)&scr2[py * 64 + 4 * qx] = colp;
    }
    __syncthreads();
    if (t < 64) {
        float s = 0.f;
        #pragma unroll
        for (int r = 0; r < 16; ++r) s += scr2[r * 64 + t];
        lpart[((long)b * 8 + pt) * TT + q0 + t] = s;
    }
}

// ============ P3: out[b,p,:] = sum_q (e[p,q]/l[q]) * qin[b,q,:] ============
// v2: DOUBLE-BUFFERED. 32p x 32d tile, 256 thr (4 waves), 4p x 4d microtile;
// each wave owns a 16-kk quarter of every 64-k chunk (k-split), LDS reduce at
// end. B staged async [k][d] into buf^1 while computing buf; A global loads
// register-prefetched TWO chunks ahead, transpose-written with linv folded in.
__global__ __launch_bounds__(256) void out_kernel(
    const float* __restrict__ ebuf, const float* __restrict__ qin,
    const float* __restrict__ lpart, float* __restrict__ out)
{
    const int b = blockIdx.z, pt = blockIdx.y, dt = blockIdx.x;
    const int m0 = pt * 32, n0 = dt * 32;
    const int t    = threadIdx.x;       // 0..255
    const int wv   = t >> 6;            // wave 0..3 -> kk quarter
    const int lane = t & 63;
    const int pg   = lane >> 3;         // p = 4*pg + i
    const int dg   = lane & 7;          // d = 4*dg + j

    __shared__ __align__(16) float As[2][64 * 36];   // 18.4 KB (also reduce scratch)
    __shared__ __align__(16) float Bs[2][64 * 32];   // 16.4 KB
    __shared__ float linv[TT];                       // 2 KB

    #pragma unroll
    for (int s = 0; s < 2; ++s) {
        int qq = t + 256 * s;
        float sum = 0.f;
        #pragma unroll
        for (int pb = 0; pb < 8; ++pb) sum += lpart[((long)b * 8 + pb) * TT + qq];
        linv[qq] = __builtin_amdgcn_rcpf(sum);
    }
    __syncthreads();   // linv ready (needed for As writes below)

    const float* Ab = ebuf + ((long)b * TT + m0) * TT;   // 32 p-rows x 512 k
    const float* Bb = qin + (long)b * TT * DD + n0;      // 512 k-rows x 32 d

    const int ar = t >> 3, ak4 = (t & 7) * 4;            // A: p-row ar, k-quads ak4, ak4+32
    const float* Arow = Ab + (long)ar * TT;
    const int bkr = t >> 3, bd4 = (t & 7) * 4;           // B: k-row bkr (+32), col-quad bd4

    // ---- prologue: stage chunk 0, prefetch A-regs for chunk 1
    stage16(Bb + (long)bkr * DD + bd4,        &Bs[0][t * 4]);
    stage16(Bb + (long)(bkr + 32) * DD + bd4, &Bs[0][1024 + t * 4]);
    float4 av0 = *(const float4*)(Arow + ak4);
    float4 av1 = *(const float4*)(Arow + ak4 + 32);
    {
        float4 l0 = *(const float4*)&linv[ak4];
        float4 l1 = *(const float4*)&linv[ak4 + 32];
        As[0][(ak4 + 0) * 36 + ar] = av0.x * l0.x;
        As[0][(ak4 + 1) * 36 + ar] = av0.y * l0.y;
        As[0][(ak4 + 2) * 36 + ar] = av0.z * l0.z;
        As[0][(ak4 + 3) * 36 + ar] = av0.w * l0.w;
        As[0][(ak4 + 32) * 36 + ar] = av1.x * l1.x;
        As[0][(ak4 + 33) * 36 + ar] = av1.y * l1.y;
        As[0][(ak4 + 34) * 36 + ar] = av1.z * l1.z;
        As[0][(ak4 + 35) * 36 + ar] = av1.w * l1.w;
    }
    av0 = *(const float4*)(Arow + 64 + ak4);
    av1 = *(const float4*)(Arow + 64 + ak4 + 32);
    __syncthreads();   // drains vmcnt: Bs[0] ready, As[0] visible

    v2f acc[4][2];
    #pragma unroll
    for (int i = 0; i < 4; ++i) { acc[i][0] = splat2(0.f); acc[i][1] = splat2(0.f); }

    int buf = 0;
    for (int c = 0; c < 8; ++c) {
        if (c < 7) {
            const int k1 = (c + 1) * 64;
            // stage B(c+1) async into buf^1
            stage16(Bb + (long)(k1 + bkr) * DD + bd4,      &Bs[buf ^ 1][t * 4]);
            stage16(Bb + (long)(k1 + 32 + bkr) * DD + bd4, &Bs[buf ^ 1][1024 + t * 4]);
            // write As(c+1) from prefetched regs, linv folded
            float4 l0 = *(const float4*)&linv[k1 + ak4];
            float4 l1 = *(const float4*)&linv[k1 + ak4 + 32];
            As[buf ^ 1][(ak4 + 0) * 36 + ar] = av0.x * l0.x;
            As[buf ^ 1][(ak4 + 1) * 36 + ar] = av0.y * l0.y;
            As[buf ^ 1][(ak4 + 2) * 36 + ar] = av0.z * l0.z;
            As[buf ^ 1][(ak4 + 3) * 36 + ar] = av0.w * l0.w;
            As[buf ^ 1][(ak4 + 32) * 36 + ar] = av1.x * l1.x;
            As[buf ^ 1][(ak4 + 33) * 36 + ar] = av1.y * l1.y;
            As[buf ^ 1][(ak4 + 34) * 36 + ar] = av1.z * l1.z;
            As[buf ^ 1][(ak4 + 35) * 36 + ar] = av1.w * l1.w;
            if (c < 6) {
                const int k2 = (c + 2) * 64;
                av0 = *(const float4*)(Arow + k2 + ak4);
                av1 = *(const float4*)(Arow + k2 + ak4 + 32);
            }
        }
        const float* as = &As[buf][0];
        const float* bs = &Bs[buf][0];
        const int kb = 16 * wv;
        #pragma unroll
        for (int u = 0; u < 16; ++u) {
            int kk = kb + u;
            float4 a  = *(const float4*)&as[kk * 36 + 4 * pg];
            float4 bq = *(const float4*)&bs[kk * 32 + 4 * dg];
            v2f b0; b0.x = bq.x; b0.y = bq.y;
            v2f b1; b1.x = bq.z; b1.y = bq.w;
            acc[0][0] = pk_fma(splat2(a.x), b0, acc[0][0]);
            acc[0][1] = pk_fma(splat2(a.x), b1, acc[0][1]);
            acc[1][0] = pk_fma(splat2(a.y), b0, acc[1][0]);
            acc[1][1] = pk_fma(splat2(a.y), b1, acc[1][1]);
            acc[2][0] = pk_fma(splat2(a.z), b0, acc[2][0]);
            acc[2][1] = pk_fma(splat2(a.z), b1, acc[2][1]);
            acc[3][0] = pk_fma(splat2(a.w), b0, acc[3][0]);
            acc[3][1] = pk_fma(splat2(a.w), b1, acc[3][1]);
        }
        __syncthreads();   // buf^1 staged (vmcnt drained), buf reads done
        buf ^= 1;
    }

    // cross-wave k reduction: scratch [w][32p][36] (reuses As[0..1], 4608 f)
    float* scr = &As[0][0];
    #pragma unroll
    for (int i = 0; i < 4; ++i) {
        *(v2f*)&scr[wv * 1152 + (4 * pg + i) * 36 + 4 * dg]     = acc[i][0];
        *(v2f*)&scr[wv * 1152 + (4 * pg + i) * 36 + 4 * dg + 2] = acc[i][1];
    }
    __syncthreads();
    {
        int pr = t >> 3, d0 = (t & 7) * 4;
        float4 s0 = *(const float4*)&scr[0 * 1152 + pr * 36 + d0];
        float4 s1 = *(const float4*)&scr[1 * 1152 + pr * 36 + d0];
        float4 s2 = *(const float4*)&scr[2 * 1152 + pr * 36 + d0];
        float4 s3 = *(const float4*)&scr[3 * 1152 + pr * 36 + d0];
        float4 v;
        v.x = (s0.x + s1.x) + (s2.x + s3.x);
        v.y = (s0.y + s1.y) + (s2.y + s3.y);
        v.z = (s0.z + s1.z) + (s2.z + s3.z);
        v.w = (s0.w + s1.w) + (s2.w + s3.w);
        *(float4*)(out + ((long)b * TT + m0 + pr) * DD + n0 + d0) = v;
    }
}

extern "C" void kernel_launch(void* const* d_in, const int* in_sizes, int n_in,
                              void* d_out, int out_size, void* d_ws, size_t ws_size,
                              hipStream_t stream) {
    const float* q  = (const float*)d_in[0];
    const float* p  = (const float*)d_in[1];
    const float* W0 = (const float*)d_in[2];
    const float* W1 = (const float*)d_in[3];
    const float* vc = (const float*)d_in[4];
    float* out = (float*)d_out;

    float* ws    = (float*)d_ws;
    float* expQ  = ws;                // [4][256][512]  e^{2*projQ}, [b][d][q]
    float* expP  = ws + 524288;       // [4][512][256]  e^{2*projP}/vc, [b][p][d]
    float* ebuf  = ws + 1048576;      // [4][512][512]
    float* lpart = ws + 2097152;      // [4][8][512]

    proj_exp_kernel<<<dim3(512), 256, 0, stream>>>(q, p, W0, W1, vc, expQ, expP);
    score_kernel<<<dim3(8, 8, NB), 512, 0, stream>>>(expP, expQ, vc, ebuf, lpart);
    out_kernel<<<dim3(8, 16, NB), 256, 0, stream>>>(ebuf, q, lpart, out);
}